// Round 3
// baseline (251.797 us; speedup 1.0000x reference)
//
#include <hip/hip_runtime.h>
#include <stdint.h>

#define NB_ 8
#define NC_ 128
#define NN_ 4096

typedef float f32x4 __attribute__((ext_vector_type(4)));
typedef _Float16 f16x8 __attribute__((ext_vector_type(8)));
typedef short s16x8 __attribute__((ext_vector_type(8)));

__device__ __forceinline__ uint16_t f2bf(float f) {
    union { float f; uint32_t u; } v; v.f = f;
    return (uint16_t)((v.u + 0x7FFFu + ((v.u >> 16) & 1u)) >> 16);
}

// ---------------- prep: build xt = fp16 x^T [N][C], xv = bf16 x [C][N] ----
__global__ __launch_bounds__(256) void prep_kernel(
        const float* __restrict__ pts, _Float16* __restrict__ xt,
        uint16_t* __restrict__ xv) {
    __shared__ float T[64][65];
    int bid = blockIdx.x;
    int ct = bid & 1, nt = (bid >> 1) & 63, b = bid >> 7;
    int c0 = ct * 64, n0 = nt * 64;
    int lr = threadIdx.x >> 6, lc = threadIdx.x & 63;
    const float* src = pts + ((size_t)b * NC_ + c0) * NN_ + n0;
#pragma unroll
    for (int r = 0; r < 16; ++r) {
        int cl = r * 4 + lr;
        float v = src[(size_t)cl * NN_ + lc];
        T[cl][lc] = v;
        xv[((size_t)b * NC_ + c0 + cl) * NN_ + n0 + lc] = f2bf(v);
    }
    __syncthreads();
#pragma unroll
    for (int r = 0; r < 16; ++r) {
        int nl = r * 4 + lr;
        xt[((size_t)b * NN_ + n0 + nl) * NC_ + c0 + lc] = (_Float16)T[lc][nl];
    }
}

// ---------------- flash: fused QK^T -> exp -> PV, fixed shift 64 ----------
// XCD-pinned: b = bid & 7 so each XCD's L2 holds one batch (2 MB << 4 MB).
// Software-pipelined: V loads issued at top of iter, K double-buffered one
// iter ahead (unroll-2 rotation with named buffers -> no scratch).
template <bool MSPLIT>
__global__ __launch_bounds__(256, 2) void flash_kernel(
        const _Float16* __restrict__ xt, const uint16_t* __restrict__ xv,
        float* __restrict__ Opart, float* __restrict__ lpart,
        const float* __restrict__ pts, const float* __restrict__ gamma,
        float* __restrict__ out) {
    int bid = blockIdx.x;
    int mh, nb, b;
    if (MSPLIT) { b = bid & 7; int rest = bid >> 3; nb = rest & 31; mh = rest >> 5; }
    else        { b = bid & 7; nb = bid >> 3; mh = 0; }
    int tid = threadIdx.x;
    int w = tid >> 6, l = tid & 63, l15 = l & 15, g = l >> 4;

    // per-wave private P transpose tile: 32 rows x 32 bf16, 80B row stride
    __shared__ __align__(16) uint16_t Plds[4][32][40];
    __shared__ float Lsh[4][32];

    int nbase = nb * 128 + w * 32;
    const _Float16* xtb = xt + (size_t)b * NN_ * NC_;
    const uint16_t* xvb = xv + (size_t)b * NC_ * NN_;

    // Q fragments: A[row=n][k=c], lane: row = l15, k = g*8+j  (k-chunks of 32)
    f16x8 q[2][4];
#pragma unroll
    for (int ns = 0; ns < 2; ++ns)
#pragma unroll
        for (int cc = 0; cc < 4; ++cc)
            q[ns][cc] = *(const f16x8*)(xtb + (size_t)(nbase + ns * 16 + l15) * NC_ + cc * 32 + g * 8);

    f32x4 acc[8][2];
#pragma unroll
    for (int cs = 0; cs < 8; ++cs)
#pragma unroll
        for (int ns = 0; ns < 2; ++ns)
            acc[cs][ns] = (f32x4){0.f, 0.f, 0.f, 0.f};
    float lsum[2][4] = {{0.f, 0.f, 0.f, 0.f}, {0.f, 0.f, 0.f, 0.f}};

    const int nsteps = MSPLIT ? 64 : 128;
    const int mstart = MSPLIT ? mh * 2048 : 0;

    // K double buffers (named, rotated by unroll-2 -> no v_mov churn, no scratch)
    f16x8 ka[2][4], kb[2][4];
#pragma unroll
    for (int ms = 0; ms < 2; ++ms)
#pragma unroll
        for (int cc = 0; cc < 4; ++cc)
            ka[ms][cc] = *(const f16x8*)(xtb + (size_t)(mstart + ms * 16 + l15) * NC_ + cc * 32 + g * 8);

#define FLASH_STEP(IT, KC, KN)                                                          \
    do {                                                                                \
        int m0 = mstart + (IT) * 32;                                                    \
        /* V fragments for this iter: issued first, consumed after exp+LDS (~400cy) */  \
        s16x8 vf[8];                                                                    \
        _Pragma("unroll")                                                               \
        for (int cs = 0; cs < 8; ++cs)                                                  \
            vf[cs] = *(const s16x8*)(xvb + (size_t)(cs * 16 + l15) * NN_ + m0 + g * 8); \
        /* prefetch next iter's K fragments */                                          \
        if ((IT) + 1 < nsteps) {                                                        \
            int m1 = m0 + 32;                                                           \
            _Pragma("unroll")                                                           \
            for (int ms = 0; ms < 2; ++ms)                                              \
                _Pragma("unroll")                                                       \
                for (int cc = 0; cc < 4; ++cc)                                          \
                    KN[ms][cc] = *(const f16x8*)(xtb + (size_t)(m1 + ms * 16 + l15) * NC_ + cc * 32 + g * 8); \
        }                                                                               \
        /* S[n][m] = sum_c x[c][n]*x[c][m] */                                           \
        f32x4 s[2][2];                                                                  \
        __builtin_amdgcn_s_setprio(1);                                                  \
        _Pragma("unroll")                                                               \
        for (int ns = 0; ns < 2; ++ns)                                                  \
            _Pragma("unroll")                                                           \
            for (int ms = 0; ms < 2; ++ms) {                                            \
                f32x4 a = (f32x4){0.f, 0.f, 0.f, 0.f};                                  \
                _Pragma("unroll")                                                       \
                for (int cc = 0; cc < 4; ++cc)                                          \
                    a = __builtin_amdgcn_mfma_f32_16x16x32_f16(q[ns][cc], KC[ms][cc], a, 0, 0, 0); \
                s[ns][ms] = a;                                                          \
            }                                                                           \
        __builtin_amdgcn_s_setprio(0);                                                  \
        /* P = exp(-(S+64)) = exp2(fma(S,-log2e,-64*log2e)); C/D: row=g*4+r, col=l15 */ \
        _Pragma("unroll")                                                               \
        for (int ns = 0; ns < 2; ++ns)                                                  \
            _Pragma("unroll")                                                           \
            for (int ms = 0; ms < 2; ++ms)                                              \
                _Pragma("unroll")                                                       \
                for (int r = 0; r < 4; ++r) {                                           \
                    float p = __expf(-(s[ns][ms][r] + 64.f));                           \
                    lsum[ns][r] += p;                                                   \
                    Plds[w][ns * 16 + g * 4 + r][ms * 16 + l15] = f2bf(p);              \
                }                                                                       \
        asm volatile("s_waitcnt lgkmcnt(0)" ::: "memory");                              \
        /* P^T fragments for PV: B[k=m][col=n] */                                       \
        s16x8 pf[2];                                                                    \
        _Pragma("unroll")                                                               \
        for (int ns = 0; ns < 2; ++ns)                                                  \
            pf[ns] = *(const s16x8*)&Plds[w][ns * 16 + l15][g * 8];                     \
        /* O[c][n] += V[c][m] * P^T[m][n] */                                            \
        __builtin_amdgcn_s_setprio(1);                                                  \
        _Pragma("unroll")                                                               \
        for (int cs = 0; cs < 8; ++cs)                                                  \
            _Pragma("unroll")                                                           \
            for (int ns = 0; ns < 2; ++ns)                                              \
                acc[cs][ns] = __builtin_amdgcn_mfma_f32_16x16x32_bf16(vf[cs], pf[ns], acc[cs][ns], 0, 0, 0); \
        __builtin_amdgcn_s_setprio(0);                                                  \
    } while (0)

    for (int it = 0; it < nsteps; it += 2) {
        FLASH_STEP(it, ka, kb);
        FLASH_STEP(it + 1, kb, ka);
    }
#undef FLASH_STEP

    // reduce lsum over the 16 lanes of each lane-group (cols m of the S tile)
#pragma unroll
    for (int ns = 0; ns < 2; ++ns)
#pragma unroll
        for (int r = 0; r < 4; ++r) {
            float v2 = lsum[ns][r];
            v2 += __shfl_xor(v2, 1, 16);
            v2 += __shfl_xor(v2, 2, 16);
            v2 += __shfl_xor(v2, 4, 16);
            v2 += __shfl_xor(v2, 8, 16);
            lsum[ns][r] = v2;
        }

    if (MSPLIT) {
        size_t obase = (size_t)((b * 32 + nb) * 2 + mh) * (128 * 128);
#pragma unroll
        for (int cs = 0; cs < 8; ++cs)
#pragma unroll
            for (int ns = 0; ns < 2; ++ns)
#pragma unroll
                for (int r = 0; r < 4; ++r)
                    Opart[obase + (size_t)(cs * 16 + g * 4 + r) * 128 + w * 32 + ns * 16 + l15] =
                        acc[cs][ns][r];
        if (l15 == 0) {
            size_t lb = (size_t)((b * 32 + nb) * 2 + mh) * 128;
#pragma unroll
            for (int ns = 0; ns < 2; ++ns)
#pragma unroll
                for (int r = 0; r < 4; ++r)
                    lpart[lb + w * 32 + ns * 16 + g * 4 + r] = lsum[ns][r];
        }
    } else {
        if (l15 == 0) {
#pragma unroll
            for (int ns = 0; ns < 2; ++ns)
#pragma unroll
                for (int r = 0; r < 4; ++r)
                    Lsh[w][ns * 16 + g * 4 + r] = lsum[ns][r];
        }
        __syncthreads();
        float gm = gamma[0];
        float linv[2];
#pragma unroll
        for (int ns = 0; ns < 2; ++ns) linv[ns] = 1.0f / Lsh[w][ns * 16 + l15];
        const float* ptsb = pts + (size_t)b * NC_ * NN_;
        float* outb = out + (size_t)b * NC_ * NN_;
#pragma unroll
        for (int cs = 0; cs < 8; ++cs)
#pragma unroll
            for (int ns = 0; ns < 2; ++ns)
#pragma unroll
                for (int r = 0; r < 4; ++r) {
                    size_t idx = (size_t)(cs * 16 + g * 4 + r) * NN_ + nbase + ns * 16 + l15;
                    outb[idx] = gm * acc[cs][ns][r] * linv[ns] + ptsb[idx];
                }
    }
}

// ---------------- epilogue (m-split combine): out = g*(O0+O1)/(l0+l1)+pts --
__global__ __launch_bounds__(256) void epi_kernel(
        const float* __restrict__ pts, const float* __restrict__ gamma,
        const float* __restrict__ Opart, const float* __restrict__ lpart,
        float* __restrict__ out) {
    size_t t = (size_t)blockIdx.x * 256 + threadIdx.x;
    size_t e = t * 4;
    int b = (int)(e >> 19);           // / (128*4096)
    int r = (int)(e & 524287);
    int c = r >> 12;
    int n = r & 4095;
    int nb = n >> 7, nl = n & 127;
    size_t ob = (size_t)((b * 32 + nb) * 2) * 16384 + (size_t)c * 128 + nl;
    f32x4 o0 = *(const f32x4*)(Opart + ob);
    f32x4 o1 = *(const f32x4*)(Opart + ob + 16384);
    size_t lb = (size_t)((b * 32 + nb) * 2) * 128 + nl;
    f32x4 l0 = *(const f32x4*)(lpart + lb);
    f32x4 l1 = *(const f32x4*)(lpart + lb + 128);
    f32x4 p = *(const f32x4*)(pts + e);
    float gm = gamma[0];
    f32x4 res;
#pragma unroll
    for (int j = 0; j < 4; ++j)
        res[j] = gm * (o0[j] + o1[j]) / (l0[j] + l1[j]) + p[j];
    *(f32x4*)(out + e) = res;
}

extern "C" void kernel_launch(void* const* d_in, const int* in_sizes, int n_in,
                              void* d_out, int out_size, void* d_ws, size_t ws_size,
                              hipStream_t stream) {
    const float* pts = (const float*)d_in[0];
    const float* gamma = (const float*)d_in[1];
    float* out = (float*)d_out;

    char* ws = (char*)d_ws;
    _Float16* xt = (_Float16*)ws;                              // 8 MB
    uint16_t* xv = (uint16_t*)(ws + 8388608);                  // 8 MB
    float* Opart = (float*)(ws + 16777216);                    // 32 MB
    float* lpart = (float*)(ws + 16777216 + 33554432);         // 256 KB
    const size_t WS_SPLIT = 16777216ull + 33554432ull + 262144ull;

    prep_kernel<<<1024, 256, 0, stream>>>(pts, xt, xv);
    if (ws_size >= WS_SPLIT) {
        flash_kernel<true><<<512, 256, 0, stream>>>(xt, xv, Opart, lpart, pts, gamma, out);
        epi_kernel<<<4096, 256, 0, stream>>>(pts, gamma, Opart, lpart, out);
    } else {
        flash_kernel<false><<<256, 256, 0, stream>>>(xt, xv, nullptr, nullptr, pts, gamma, out);
    }
}

// Round 4
// 113.972 us; speedup vs baseline: 2.2093x; 2.2093x over previous
//
#include <hip/hip_runtime.h>
#include <stdint.h>

#define NB_ 8
#define NC_ 128
#define NN_ 4096

typedef float f32x4 __attribute__((ext_vector_type(4)));
typedef _Float16 f16x8 __attribute__((ext_vector_type(8)));
typedef short s16x8 __attribute__((ext_vector_type(8)));

__device__ __forceinline__ uint16_t f2bf(float f) {
    union { float f; uint32_t u; } v; v.f = f;
    return (uint16_t)((v.u + 0x7FFFu + ((v.u >> 16) & 1u)) >> 16);
}

// ---------------- prep: build xt = fp16 x^T [N][C], xv = bf16 x [C][N] ----
__global__ __launch_bounds__(256) void prep_kernel(
        const float* __restrict__ pts, _Float16* __restrict__ xt,
        uint16_t* __restrict__ xv) {
    __shared__ float T[64][65];
    int bid = blockIdx.x;
    int ct = bid & 1, nt = (bid >> 1) & 63, b = bid >> 7;
    int c0 = ct * 64, n0 = nt * 64;
    int lr = threadIdx.x >> 6, lc = threadIdx.x & 63;
    const float* src = pts + ((size_t)b * NC_ + c0) * NN_ + n0;
#pragma unroll
    for (int r = 0; r < 16; ++r) {
        int cl = r * 4 + lr;
        float v = src[(size_t)cl * NN_ + lc];
        T[cl][lc] = v;
        xv[((size_t)b * NC_ + c0 + cl) * NN_ + n0 + lc] = f2bf(v);
    }
    __syncthreads();
#pragma unroll
    for (int r = 0; r < 16; ++r) {
        int nl = r * 4 + lr;
        xt[((size_t)b * NN_ + n0 + nl) * NC_ + c0 + lc] = (_Float16)T[lc][nl];
    }
}

// ---------------- flash: fused QK^T -> exp -> PV, fixed shift 64 ----------
// K/V tiles staged in LDS once per block (shared by 4 waves). K-tile XOR-
// swizzled (chunk ^= row&7, write+read), V-tile 80B-padded rows. Single
// buffer, 2 barriers/iter; next tile's global loads issued at top of iter
// (T14 split). XCD-pinned b = bid & 7.
template <bool MSPLIT>
__global__ __launch_bounds__(256, 2) void flash_kernel(
        const _Float16* __restrict__ xt, const uint16_t* __restrict__ xv,
        float* __restrict__ Opart, float* __restrict__ lpart,
        const float* __restrict__ pts, const float* __restrict__ gamma,
        float* __restrict__ out) {
    int bid = blockIdx.x;
    int mh, nb, b;
    if (MSPLIT) { b = bid & 7; int rest = bid >> 3; nb = rest & 31; mh = rest >> 5; }
    else        { b = bid & 7; nb = bid >> 3; mh = 0; }
    int tid = threadIdx.x;
    int w = tid >> 6, l = tid & 63, l15 = l & 15, g = l >> 4;

    __shared__ __align__(16) uint16_t Kt[32 * 128];   // fp16 bits, [row][chunk^ (row&7)]
    __shared__ __align__(16) uint16_t Vt[128 * 40];   // bf16, 80B row stride
    __shared__ __align__(16) uint16_t Plds[4][32][40];
    __shared__ float Lsh[4][32];

    int nbase = nb * 128 + w * 32;
    const _Float16* xtb = xt + (size_t)b * NN_ * NC_;
    const uint16_t* xvb = xv + (size_t)b * NC_ * NN_;

    // staging assignment (256 threads, 16 KB/iter)
    int kRow = tid >> 3, kC2 = (tid & 7) * 2;      // K: row 0..31, 2 chunks of 8 f16
    int vRow = tid >> 1, vC = (tid & 1) * 16;      // V: row 0..127, 16 bf16
    const uint16_t* kSrcB = (const uint16_t*)xtb + (size_t)kRow * NC_ + kC2 * 8;
    const uint16_t* vSrcB = xvb + (size_t)vRow * NN_ + vC;
    uint16_t* kDstA = Kt + kRow * 128 + ((kC2 ^ (kRow & 7)) * 8);
    uint16_t* kDstB = Kt + kRow * 128 + (((kC2 + 1) ^ (kRow & 7)) * 8);
    uint16_t* vDst = Vt + vRow * 40 + vC;

    // Q fragments: A[row=n][k=c], lane: row = l15, k = g*8+j  (k-chunks of 32)
    f16x8 q[2][4];
#pragma unroll
    for (int ns = 0; ns < 2; ++ns)
#pragma unroll
        for (int cc = 0; cc < 4; ++cc)
            q[ns][cc] = *(const f16x8*)(xtb + (size_t)(nbase + ns * 16 + l15) * NC_ + cc * 32 + g * 8);

    f32x4 acc[8][2];
#pragma unroll
    for (int cs = 0; cs < 8; ++cs)
#pragma unroll
        for (int ns = 0; ns < 2; ++ns)
            acc[cs][ns] = (f32x4){0.f, 0.f, 0.f, 0.f};
    float lsum[2][4] = {{0.f, 0.f, 0.f, 0.f}, {0.f, 0.f, 0.f, 0.f}};

    const int nsteps = MSPLIT ? 64 : 128;
    const int mstart = MSPLIT ? mh * 2048 : 0;

    // prologue: stage tile 0
    s16x8 kn0 = *(const s16x8*)(kSrcB + (size_t)mstart * NC_);
    s16x8 kn1 = *(const s16x8*)(kSrcB + (size_t)mstart * NC_ + 8);
    s16x8 vn0 = *(const s16x8*)(vSrcB + mstart);
    s16x8 vn1 = *(const s16x8*)(vSrcB + mstart + 8);
    *(s16x8*)kDstA = kn0;
    *(s16x8*)kDstB = kn1;
    *(s16x8*)vDst = vn0;
    *(s16x8*)(vDst + 8) = vn1;
    __syncthreads();

    int krx = l15 & 7;

    for (int it = 0; it < nsteps; ++it) {
        int m0 = mstart + it * 32;
        bool more = (it + 1) < nsteps;
        // issue next tile's global loads early (written after barrier #1)
        if (more) {
            int m1 = m0 + 32;
            kn0 = *(const s16x8*)(kSrcB + (size_t)m1 * NC_);
            kn1 = *(const s16x8*)(kSrcB + (size_t)m1 * NC_ + 8);
            vn0 = *(const s16x8*)(vSrcB + m1);
            vn1 = *(const s16x8*)(vSrcB + m1 + 8);
        }

        // K fragments from LDS (swizzled): B[k=c][col=m], lane: col = l15
        f16x8 kf[2][4];
#pragma unroll
        for (int ms = 0; ms < 2; ++ms)
#pragma unroll
            for (int cc = 0; cc < 4; ++cc)
                kf[ms][cc] = *(const f16x8*)(Kt + (ms * 16 + l15) * 128 + (((cc * 4 + g) ^ krx) * 8));

        // S[n][m] = sum_c x[c][n]*x[c][m]
        f32x4 s[2][2];
        __builtin_amdgcn_s_setprio(1);
#pragma unroll
        for (int ns = 0; ns < 2; ++ns)
#pragma unroll
            for (int ms = 0; ms < 2; ++ms) {
                f32x4 a = (f32x4){0.f, 0.f, 0.f, 0.f};
#pragma unroll
                for (int cc = 0; cc < 4; ++cc)
                    a = __builtin_amdgcn_mfma_f32_16x16x32_f16(q[ns][cc], kf[ms][cc], a, 0, 0, 0);
                s[ns][ms] = a;
            }
        __builtin_amdgcn_s_setprio(0);

        // P = exp(-(S+64)); C/D layout: row n = g*4+r, col m = l15.
#pragma unroll
        for (int ns = 0; ns < 2; ++ns)
#pragma unroll
            for (int ms = 0; ms < 2; ++ms)
#pragma unroll
                for (int r = 0; r < 4; ++r) {
                    float p = __expf(-(s[ns][ms][r] + 64.f));
                    lsum[ns][r] += p;
                    Plds[w][ns * 16 + g * 4 + r][ms * 16 + l15] = f2bf(p);
                }
        asm volatile("s_waitcnt lgkmcnt(0)" ::: "memory");

        // P^T fragments for PV: B[k=m][col=n], lane: col = l15, k = g*8+j
        s16x8 pf[2];
#pragma unroll
        for (int ns = 0; ns < 2; ++ns)
            pf[ns] = *(const s16x8*)&Plds[w][ns * 16 + l15][g * 8];

        // O[c][n] += V[c][m] * P^T[m][n]; V frag from LDS: A[row=c][k=m]
        __builtin_amdgcn_s_setprio(1);
#pragma unroll
        for (int cs = 0; cs < 8; ++cs) {
            s16x8 vf = *(const s16x8*)(Vt + (cs * 16 + l15) * 40 + g * 8);
#pragma unroll
            for (int ns = 0; ns < 2; ++ns)
                acc[cs][ns] = __builtin_amdgcn_mfma_f32_16x16x32_bf16(vf, pf[ns], acc[cs][ns], 0, 0, 0);
        }
        __builtin_amdgcn_s_setprio(0);

        __syncthreads();   // all waves done reading current tile
        if (more) {
            *(s16x8*)kDstA = kn0;
            *(s16x8*)kDstB = kn1;
            *(s16x8*)vDst = vn0;
            *(s16x8*)(vDst + 8) = vn1;
        }
        __syncthreads();   // new tile visible
    }

    // reduce lsum over the 16 lanes of each lane-group (cols m of the S tile)
#pragma unroll
    for (int ns = 0; ns < 2; ++ns)
#pragma unroll
        for (int r = 0; r < 4; ++r) {
            float v2 = lsum[ns][r];
            v2 += __shfl_xor(v2, 1, 16);
            v2 += __shfl_xor(v2, 2, 16);
            v2 += __shfl_xor(v2, 4, 16);
            v2 += __shfl_xor(v2, 8, 16);
            lsum[ns][r] = v2;
        }

    if (MSPLIT) {
        size_t obase = (size_t)((b * 32 + nb) * 2 + mh) * (128 * 128);
#pragma unroll
        for (int cs = 0; cs < 8; ++cs)
#pragma unroll
            for (int ns = 0; ns < 2; ++ns)
#pragma unroll
                for (int r = 0; r < 4; ++r)
                    Opart[obase + (size_t)(cs * 16 + g * 4 + r) * 128 + w * 32 + ns * 16 + l15] =
                        acc[cs][ns][r];
        if (l15 == 0) {
            size_t lb = (size_t)((b * 32 + nb) * 2 + mh) * 128;
#pragma unroll
            for (int ns = 0; ns < 2; ++ns)
#pragma unroll
                for (int r = 0; r < 4; ++r)
                    lpart[lb + w * 32 + ns * 16 + g * 4 + r] = lsum[ns][r];
        }
    } else {
        if (l15 == 0) {
#pragma unroll
            for (int ns = 0; ns < 2; ++ns)
#pragma unroll
                for (int r = 0; r < 4; ++r)
                    Lsh[w][ns * 16 + g * 4 + r] = lsum[ns][r];
        }
        __syncthreads();
        float gm = gamma[0];
        float linv[2];
#pragma unroll
        for (int ns = 0; ns < 2; ++ns) linv[ns] = 1.0f / Lsh[w][ns * 16 + l15];
        const float* ptsb = pts + (size_t)b * NC_ * NN_;
        float* outb = out + (size_t)b * NC_ * NN_;
#pragma unroll
        for (int cs = 0; cs < 8; ++cs)
#pragma unroll
            for (int ns = 0; ns < 2; ++ns)
#pragma unroll
                for (int r = 0; r < 4; ++r) {
                    size_t idx = (size_t)(cs * 16 + g * 4 + r) * NN_ + nbase + ns * 16 + l15;
                    outb[idx] = gm * acc[cs][ns][r] * linv[ns] + ptsb[idx];
                }
    }
}

// ---------------- epilogue (m-split combine): out = g*(O0+O1)/(l0+l1)+pts --
__global__ __launch_bounds__(256) void epi_kernel(
        const float* __restrict__ pts, const float* __restrict__ gamma,
        const float* __restrict__ Opart, const float* __restrict__ lpart,
        float* __restrict__ out) {
    size_t t = (size_t)blockIdx.x * 256 + threadIdx.x;
    size_t e = t * 4;
    int b = (int)(e >> 19);           // / (128*4096)
    int r = (int)(e & 524287);
    int c = r >> 12;
    int n = r & 4095;
    int nb = n >> 7, nl = n & 127;
    size_t ob = (size_t)((b * 32 + nb) * 2) * 16384 + (size_t)c * 128 + nl;
    f32x4 o0 = *(const f32x4*)(Opart + ob);
    f32x4 o1 = *(const f32x4*)(Opart + ob + 16384);
    size_t lb = (size_t)((b * 32 + nb) * 2) * 128 + nl;
    f32x4 l0 = *(const f32x4*)(lpart + lb);
    f32x4 l1 = *(const f32x4*)(lpart + lb + 128);
    f32x4 p = *(const f32x4*)(pts + e);
    float gm = gamma[0];
    f32x4 res;
#pragma unroll
    for (int j = 0; j < 4; ++j)
        res[j] = gm * (o0[j] + o1[j]) / (l0[j] + l1[j]) + p[j];
    *(f32x4*)(out + e) = res;
}

extern "C" void kernel_launch(void* const* d_in, const int* in_sizes, int n_in,
                              void* d_out, int out_size, void* d_ws, size_t ws_size,
                              hipStream_t stream) {
    const float* pts = (const float*)d_in[0];
    const float* gamma = (const float*)d_in[1];
    float* out = (float*)d_out;

    char* ws = (char*)d_ws;
    _Float16* xt = (_Float16*)ws;                              // 8 MB
    uint16_t* xv = (uint16_t*)(ws + 8388608);                  // 8 MB
    float* Opart = (float*)(ws + 16777216);                    // 32 MB
    float* lpart = (float*)(ws + 16777216 + 33554432);         // 256 KB
    const size_t WS_SPLIT = 16777216ull + 33554432ull + 262144ull;

    prep_kernel<<<1024, 256, 0, stream>>>(pts, xt, xv);
    if (ws_size >= WS_SPLIT) {
        flash_kernel<true><<<512, 256, 0, stream>>>(xt, xv, Opart, lpart, pts, gamma, out);
        epi_kernel<<<4096, 256, 0, stream>>>(pts, gamma, Opart, lpart, out);
    } else {
        flash_kernel<false><<<256, 256, 0, stream>>>(xt, xv, nullptr, nullptr, pts, gamma, out);
    }
}